// Round 1
// baseline (472.275 us; speedup 1.0000x reference)
//
#include <hip/hip_runtime.h>

#define CIN   32
#define COUT  64
#define K_OFF 27
#define BN    64   // output rows per block

// ---------------------------------------------------------------------------
// Mask-dtype detection: jax bool may arrive as 1-byte bool or int32.
// If any byte at offset %4 != 0 is nonzero -> 1-byte bool (flag=1),
// else -> int32 (flag=0). Mask is ~50% ones so 64KB sample is decisive.
// ---------------------------------------------------------------------------
__global__ void detect_mask_dtype(const unsigned char* __restrict__ mask,
                                  int nbytes, int* __restrict__ flag) {
    __shared__ int any;
    if (threadIdx.x == 0) any = 0;
    __syncthreads();
    int found = 0;
    for (int i = threadIdx.x; i < nbytes; i += blockDim.x) {
        if ((i & 3) && mask[i]) found = 1;
    }
    if (found) atomicOr(&any, 1);
    __syncthreads();
    if (threadIdx.x == 0) *flag = any;
}

// ---------------------------------------------------------------------------
// Sparse conv: out[n, :] = sum_k mask[k,n] * feat[nmap[k,n], :] @ W[k]
// Block: 256 threads, 64 output rows. Per k: stage W[k] (8KB) + gathered
// A^T tile (8KB) in LDS, each thread accumulates a 4x4 (row x cout) tile.
// ---------------------------------------------------------------------------
__global__ __launch_bounds__(256) void sparse_conv_kernel(
    const float* __restrict__ feat,          // [N, CIN]
    const int*   __restrict__ nmap,          // [K, N]
    const unsigned char* __restrict__ mask8, // [K, N] (if flag==1)
    const int*   __restrict__ mask32,        // [K, N] (if flag==0)
    const float* __restrict__ wk,            // [K, CIN, COUT]
    float* __restrict__ out,                 // [N, COUT]
    int n, const int* __restrict__ flag)
{
    __shared__ float A[CIN][BN];    // gathered features, transposed
    __shared__ float W[CIN][COUT];  // current offset's weights

    const int tid   = threadIdx.x;
    const int n0    = blockIdx.x * BN;
    const int is_b8 = *flag;        // wave-uniform

    // compute-phase mapping: 16 row-groups x 16 cout-groups
    const int r0 = (tid >> 4) * 4;  // 0,4,...,60
    const int c0 = (tid & 15) * 4;  // 0,4,...,60

    // gather-phase mapping: 64 rows x 4 parts (8 floats each)
    const int grow  = tid >> 2;     // 0..63
    const int gpart = tid & 3;      // 0..3

    float acc[4][4] = {};

    for (int k = 0; k < K_OFF; ++k) {
        // ---- stage W[k]: 2048 floats, 8 per thread (two float4) ----
        {
            const int base = tid * 8;
            const float* wsrc = wk + (size_t)k * (CIN * COUT) + base;
            float4 w0 = ((const float4*)wsrc)[0];
            float4 w1 = ((const float4*)wsrc)[1];
            const int wr = base >> 6;   // / COUT
            const int wc = base & 63;   // % COUT
            *(float4*)&W[wr][wc]     = w0;
            *(float4*)&W[wr][wc + 4] = w1;
        }
        // ---- gather A tile (transposed store) ----
        {
            const int gn  = n0 + grow;
            float4 f0 = make_float4(0.f, 0.f, 0.f, 0.f);
            float4 f1 = f0;
            if (gn < n) {
                const int idx = k * n + gn;
                const int m   = is_b8 ? (int)mask8[idx] : mask32[idx];
                if (m) {
                    const int src = nmap[idx];
                    const float* fsrc = feat + (size_t)src * CIN + gpart * 8;
                    f0 = ((const float4*)fsrc)[0];
                    f1 = ((const float4*)fsrc)[1];
                }
            }
            const int cb = gpart * 8;
            A[cb + 0][grow] = f0.x;
            A[cb + 1][grow] = f0.y;
            A[cb + 2][grow] = f0.z;
            A[cb + 3][grow] = f0.w;
            A[cb + 4][grow] = f1.x;
            A[cb + 5][grow] = f1.y;
            A[cb + 6][grow] = f1.z;
            A[cb + 7][grow] = f1.w;
        }
        __syncthreads();

        // ---- 4x4 register-tile FMA over CIN ----
        #pragma unroll
        for (int c = 0; c < CIN; ++c) {
            const float4 a = *(const float4*)&A[c][r0];
            const float4 w = *(const float4*)&W[c][c0];
            acc[0][0] += a.x * w.x; acc[0][1] += a.x * w.y;
            acc[0][2] += a.x * w.z; acc[0][3] += a.x * w.w;
            acc[1][0] += a.y * w.x; acc[1][1] += a.y * w.y;
            acc[1][2] += a.y * w.z; acc[1][3] += a.y * w.w;
            acc[2][0] += a.z * w.x; acc[2][1] += a.z * w.y;
            acc[2][2] += a.z * w.z; acc[2][3] += a.z * w.w;
            acc[3][0] += a.w * w.x; acc[3][1] += a.w * w.y;
            acc[3][2] += a.w * w.z; acc[3][3] += a.w * w.w;
        }
        __syncthreads();
    }

    // ---- epilogue: 4 rows x float4 per thread ----
    #pragma unroll
    for (int i = 0; i < 4; ++i) {
        const int orow = n0 + r0 + i;
        if (orow < n) {
            float4 v = make_float4(acc[i][0], acc[i][1], acc[i][2], acc[i][3]);
            *(float4*)&out[(size_t)orow * COUT + c0] = v;
        }
    }
}

extern "C" void kernel_launch(void* const* d_in, const int* in_sizes, int n_in,
                              void* d_out, int out_size, void* d_ws, size_t ws_size,
                              hipStream_t stream) {
    const float*         feat = (const float*)d_in[0];
    const int*           nmap = (const int*)d_in[1];
    const unsigned char* m8   = (const unsigned char*)d_in[2];
    const int*           m32  = (const int*)d_in[2];
    const float*         wk   = (const float*)d_in[3];
    float*               out  = (float*)d_out;

    const int n = in_sizes[0] / CIN;
    int* flag = (int*)d_ws;

    detect_mask_dtype<<<1, 256, 0, stream>>>(m8, 65536, flag);

    const int nblocks = (n + BN - 1) / BN;
    sparse_conv_kernel<<<nblocks, 256, 0, stream>>>(feat, nmap, m8, m32, wk,
                                                    out, n, flag);
}

// Round 2
// 208.549 us; speedup vs baseline: 2.2646x; 2.2646x over previous
//
#include <hip/hip_runtime.h>

#define CIN   32
#define COUT  64
#define K_OFF 27

typedef __attribute__((ext_vector_type(8))) short bf16x8;
typedef __attribute__((ext_vector_type(4))) float f32x4;

__device__ inline unsigned short f2bf_rne(float f) {
    union { float f; unsigned int u; } v; v.f = f;
    unsigned int u = v.u;
    u = (u + 0x7fffu + ((u >> 16) & 1u)) >> 16;
    return (unsigned short)u;
}

// ---------------------------------------------------------------------------
// Mask-dtype detection (parallel): bytes at offset %4 != 0 nonzero => 1-byte
// bool (flag=1); all zero => int32 (flag=0). flag must be memset to 0 first.
// ---------------------------------------------------------------------------
__global__ __launch_bounds__(256) void detect_mask_dtype(
    const unsigned char* __restrict__ mask, int nbytes, int* __restrict__ flag) {
    int found = 0;
    for (int i = blockIdx.x * blockDim.x + threadIdx.x; i < nbytes;
         i += gridDim.x * blockDim.x) {
        if ((i & 3) && mask[i]) found = 1;
    }
    unsigned long long b = __ballot(found);
    if ((threadIdx.x & 63) == 0 && b) atomicOr(flag, 1);
}

// features fp32 [N,CIN] -> bf16 (RNE), 8 elements/thread
__global__ __launch_bounds__(256) void cvt_feat(
    const float* __restrict__ f, unsigned short* __restrict__ o, int nelem) {
    const int base = (blockIdx.x * 256 + threadIdx.x) * 8;
    if (base >= nelem) return;
    float4 a = *(const float4*)(f + base);
    float4 b = *(const float4*)(f + base + 4);
    bf16x8 v;
    v[0] = (short)f2bf_rne(a.x); v[1] = (short)f2bf_rne(a.y);
    v[2] = (short)f2bf_rne(a.z); v[3] = (short)f2bf_rne(a.w);
    v[4] = (short)f2bf_rne(b.x); v[5] = (short)f2bf_rne(b.y);
    v[6] = (short)f2bf_rne(b.z); v[7] = (short)f2bf_rne(b.w);
    *(bf16x8*)(o + base) = v;
}

// weights fp32 [K][CIN][COUT] -> bf16 transposed [K][COUT][CIN]
__global__ __launch_bounds__(256) void cvt_wt(
    const float* __restrict__ w, unsigned short* __restrict__ o, int nelem) {
    const int e = blockIdx.x * 256 + threadIdx.x;
    if (e >= nelem) return;
    const int k   = e / (COUT * CIN);
    const int rem = e % (COUT * CIN);
    const int col = rem / CIN;
    const int cin = rem % CIN;
    o[e] = (short)f2bf_rne(w[k * (CIN * COUT) + cin * COUT + col]);
}

// ---------------------------------------------------------------------------
// Main MFMA kernel. Barrier-free, no LDS. Block = 4 waves; each wave owns
// 32 rows x 64 couts. Per k offset: 2 A-frag global gathers (masked-skip),
// 4 B-frag reads from transposed weights (wave-contiguous 1KB tile),
// 8x mfma_f32_16x16x32_bf16 (K=32=CIN in one instruction).
// ---------------------------------------------------------------------------
__global__ __launch_bounds__(256) void conv_mfma(
    const unsigned short* __restrict__ featb,   // [N][CIN] bf16
    const int*            __restrict__ nmap,    // [K][N]
    const unsigned char*  __restrict__ mask8,   // if flag==1
    const int*            __restrict__ mask32,  // if flag==0
    const unsigned short* __restrict__ wt,      // [K][COUT][CIN] bf16
    float* __restrict__ out,                    // [N][COUT]
    int n, const int* __restrict__ flag)
{
    const int tid  = threadIdx.x;
    const int wave = tid >> 6;
    const int lane = tid & 63;
    const int lrow = lane & 15;   // MFMA m / n index
    const int q    = lane >> 4;   // k-group
    const int n0   = blockIdx.x * 128 + wave * 32;
    const int is_b8 = *flag;      // wave-uniform

    f32x4 acc[2][4] = {};

    for (int k = 0; k < K_OFF; ++k) {
        bf16x8 a[2];
        #pragma unroll
        for (int rt = 0; rt < 2; ++rt) {
            bf16x8 av = {0, 0, 0, 0, 0, 0, 0, 0};
            const int row = n0 + rt * 16 + lrow;
            if (row < n) {
                const int idx = k * n + row;
                const int m = is_b8 ? (int)mask8[idx] : mask32[idx];
                if (m) {
                    const int src = nmap[idx];
                    av = *(const bf16x8*)(featb + (size_t)src * CIN + q * 8);
                }
            }
            a[rt] = av;
        }
        const unsigned short* wkp = wt + k * (COUT * CIN) + lrow * CIN + q * 8;
        #pragma unroll
        for (int ct = 0; ct < 4; ++ct) {
            bf16x8 b = *(const bf16x8*)(wkp + ct * 16 * CIN);
            acc[0][ct] = __builtin_amdgcn_mfma_f32_16x16x32_bf16(a[0], b, acc[0][ct], 0, 0, 0);
            acc[1][ct] = __builtin_amdgcn_mfma_f32_16x16x32_bf16(a[1], b, acc[1][ct], 0, 0, 0);
        }
    }

    // epilogue: C/D layout col=lane&15, row=q*4+reg
    #pragma unroll
    for (int rt = 0; rt < 2; ++rt) {
        #pragma unroll
        for (int ct = 0; ct < 4; ++ct) {
            #pragma unroll
            for (int r = 0; r < 4; ++r) {
                const int row = n0 + rt * 16 + q * 4 + r;
                if (row < n) out[(size_t)row * COUT + ct * 16 + lrow] = acc[rt][ct][r];
            }
        }
    }
}

// ---------------------------------------------------------------------------
// Fallback fp32 kernel (round-1) if ws too small for bf16 staging.
// ---------------------------------------------------------------------------
#define BN 64
__global__ __launch_bounds__(256) void sparse_conv_fp32(
    const float* __restrict__ feat, const int* __restrict__ nmap,
    const unsigned char* __restrict__ mask8, const int* __restrict__ mask32,
    const float* __restrict__ wk, float* __restrict__ out,
    int n, const int* __restrict__ flag)
{
    __shared__ float A[CIN][BN];
    __shared__ float W[CIN][COUT];
    const int tid = threadIdx.x;
    const int n0 = blockIdx.x * BN;
    const int is_b8 = *flag;
    const int r0 = (tid >> 4) * 4, c0 = (tid & 15) * 4;
    const int grow = tid >> 2, gpart = tid & 3;
    float acc[4][4] = {};
    for (int k = 0; k < K_OFF; ++k) {
        {
            const int base = tid * 8;
            const float* wsrc = wk + (size_t)k * (CIN * COUT) + base;
            float4 w0 = ((const float4*)wsrc)[0];
            float4 w1 = ((const float4*)wsrc)[1];
            *(float4*)&W[base >> 6][base & 63] = w0;
            *(float4*)&W[base >> 6][(base & 63) + 4] = w1;
        }
        {
            const int gn = n0 + grow;
            float4 f0 = make_float4(0.f, 0.f, 0.f, 0.f), f1 = f0;
            if (gn < n) {
                const int idx = k * n + gn;
                const int m = is_b8 ? (int)mask8[idx] : mask32[idx];
                if (m) {
                    const float* fsrc = feat + (size_t)nmap[idx] * CIN + gpart * 8;
                    f0 = ((const float4*)fsrc)[0];
                    f1 = ((const float4*)fsrc)[1];
                }
            }
            const int cb = gpart * 8;
            A[cb+0][grow]=f0.x; A[cb+1][grow]=f0.y; A[cb+2][grow]=f0.z; A[cb+3][grow]=f0.w;
            A[cb+4][grow]=f1.x; A[cb+5][grow]=f1.y; A[cb+6][grow]=f1.z; A[cb+7][grow]=f1.w;
        }
        __syncthreads();
        #pragma unroll
        for (int c = 0; c < CIN; ++c) {
            const float4 a = *(const float4*)&A[c][r0];
            const float4 w = *(const float4*)&W[c][c0];
            acc[0][0]+=a.x*w.x; acc[0][1]+=a.x*w.y; acc[0][2]+=a.x*w.z; acc[0][3]+=a.x*w.w;
            acc[1][0]+=a.y*w.x; acc[1][1]+=a.y*w.y; acc[1][2]+=a.y*w.z; acc[1][3]+=a.y*w.w;
            acc[2][0]+=a.z*w.x; acc[2][1]+=a.z*w.y; acc[2][2]+=a.z*w.z; acc[2][3]+=a.z*w.w;
            acc[3][0]+=a.w*w.x; acc[3][1]+=a.w*w.y; acc[3][2]+=a.w*w.z; acc[3][3]+=a.w*w.w;
        }
        __syncthreads();
    }
    #pragma unroll
    for (int i = 0; i < 4; ++i) {
        const int orow = n0 + r0 + i;
        if (orow < n)
            *(float4*)&out[(size_t)orow * COUT + c0] =
                make_float4(acc[i][0], acc[i][1], acc[i][2], acc[i][3]);
    }
}

extern "C" void kernel_launch(void* const* d_in, const int* in_sizes, int n_in,
                              void* d_out, int out_size, void* d_ws, size_t ws_size,
                              hipStream_t stream) {
    const float*         feat = (const float*)d_in[0];
    const int*           nmap = (const int*)d_in[1];
    const unsigned char* m8   = (const unsigned char*)d_in[2];
    const int*           m32  = (const int*)d_in[2];
    const float*         wk   = (const float*)d_in[3];
    float*               out  = (float*)d_out;

    const int n = in_sizes[0] / CIN;
    int* flag = (int*)d_ws;

    // ws layout: [0..4) flag | [64 ..) feat_bf16 (n*CIN*2 B) | wt_bf16 (K*COUT*CIN*2 B)
    const size_t feat_off = 64;
    const size_t feat_bytes = (size_t)n * CIN * 2;
    const size_t wt_off = feat_off + feat_bytes;
    const size_t wt_bytes = (size_t)K_OFF * COUT * CIN * 2;
    const size_t needed = wt_off + wt_bytes;

    hipMemsetAsync(flag, 0, 4, stream);
    detect_mask_dtype<<<64, 256, 0, stream>>>(m8, 65536, flag);

    if (ws_size >= needed) {
        unsigned short* featb = (unsigned short*)((char*)d_ws + feat_off);
        unsigned short* wtb   = (unsigned short*)((char*)d_ws + wt_off);
        const int nfeat = n * CIN;
        cvt_feat<<<(nfeat / 8 + 255) / 256, 256, 0, stream>>>(feat, featb, nfeat);
        const int nwt = K_OFF * COUT * CIN;
        cvt_wt<<<(nwt + 255) / 256, 256, 0, stream>>>(wk, wtb, nwt);
        const int nblocks = (n + 127) / 128;
        conv_mfma<<<nblocks, 256, 0, stream>>>(featb, nmap, m8, m32, wtb, out, n, flag);
    } else {
        const int nblocks = (n + BN - 1) / BN;
        sparse_conv_fp32<<<nblocks, 256, 0, stream>>>(feat, nmap, m8, m32, wk, out, n, flag);
    }
}

// Round 3
// 187.448 us; speedup vs baseline: 2.5195x; 1.1126x over previous
//
#include <hip/hip_runtime.h>

#define CIN   32
#define COUT  64
#define K_OFF 27

typedef __attribute__((ext_vector_type(8))) short bf16x8;
typedef __attribute__((ext_vector_type(4))) float f32x4;

__device__ inline unsigned short f2bf_rne(float f) {
    union { float f; unsigned int u; } v; v.f = f;
    unsigned int u = v.u;
    u = (u + 0x7fffu + ((u >> 16) & 1u)) >> 16;
    return (unsigned short)u;
}

// ---------------------------------------------------------------------------
// Mask-dtype detect, single block, no atomics/memset: any nonzero byte at
// offset %4 != 0  =>  1-byte bool (flag=1), else int32 (flag=0).
// ---------------------------------------------------------------------------
__global__ __launch_bounds__(1024) void detect_mask(
    const unsigned char* __restrict__ mask, int nbytes, int* __restrict__ flag) {
    __shared__ int wany[16];
    int found = 0;
    for (int i = threadIdx.x; i < nbytes; i += 1024)
        if ((i & 3) && mask[i]) found = 1;
    unsigned long long b = __ballot(found);
    if ((threadIdx.x & 63) == 0) wany[threadIdx.x >> 6] = b ? 1 : 0;
    __syncthreads();
    if (threadIdx.x == 0) {
        int any = 0;
        #pragma unroll
        for (int i = 0; i < 16; ++i) any |= wany[i];
        *flag = any;
    }
}

// ---------------------------------------------------------------------------
// Fused prep: [0,Bf) feat fp32->bf16 | [Bf,Bf+Bm) midx = mask?nmap:-1 |
// [Bf+Bm,..) weights fp32 [K][CIN][COUT] -> bf16 fragment-order
// wt2[k][ct][lane][8] so a wave's B-frag load is lane-contiguous.
// ---------------------------------------------------------------------------
__global__ __launch_bounds__(256) void prep_kernel(
    const float* __restrict__ feat, const int* __restrict__ nmap,
    const unsigned char* __restrict__ mask8, const int* __restrict__ mask32,
    const float* __restrict__ wk,
    unsigned short* __restrict__ featb, int* __restrict__ midx,
    unsigned short* __restrict__ wt2,
    int n, int Bf, int Bm, const int* __restrict__ flag)
{
    const int gid = blockIdx.x;
    if (gid < Bf) {
        const int base = (gid * 256 + threadIdx.x) * 8;
        const int nfeat = n * CIN;             // CIN=32 -> always %8==0
        if (base < nfeat) {
            float4 a = *(const float4*)(feat + base);
            float4 b = *(const float4*)(feat + base + 4);
            bf16x8 v;
            v[0] = (short)f2bf_rne(a.x); v[1] = (short)f2bf_rne(a.y);
            v[2] = (short)f2bf_rne(a.z); v[3] = (short)f2bf_rne(a.w);
            v[4] = (short)f2bf_rne(b.x); v[5] = (short)f2bf_rne(b.y);
            v[6] = (short)f2bf_rne(b.z); v[7] = (short)f2bf_rne(b.w);
            *(bf16x8*)(featb + base) = v;
        }
    } else if (gid < Bf + Bm) {
        const int t = (gid - Bf) * 256 + threadIdx.x;
        int i = t * 4;
        const int total = K_OFF * n;
        const int is_b8 = *flag;
        if (i + 3 < total) {
            int4 nm = *(const int4*)(nmap + i);
            int m0, m1, m2, m3;
            if (is_b8) {
                uchar4 mb = *(const uchar4*)(mask8 + i);
                m0 = mb.x; m1 = mb.y; m2 = mb.z; m3 = mb.w;
            } else {
                int4 mm = *(const int4*)(mask32 + i);
                m0 = mm.x; m1 = mm.y; m2 = mm.z; m3 = mm.w;
            }
            int4 r;
            r.x = m0 ? nm.x : -1; r.y = m1 ? nm.y : -1;
            r.z = m2 ? nm.z : -1; r.w = m3 ? nm.w : -1;
            *(int4*)(midx + i) = r;
        } else {
            for (; i < total; ++i) {
                int m = is_b8 ? (int)mask8[i] : mask32[i];
                midx[i] = m ? nmap[i] : -1;
            }
        }
    } else {
        const int t = (gid - Bf - Bm) * 256 + threadIdx.x;  // fragment id
        if (t < K_OFF * 4 * 64) {
            const int lane = t & 63, ct = (t >> 6) & 3, k = t >> 8;
            const int lrow = lane & 15, q = lane >> 4;
            const int col = ct * 16 + lrow;
            bf16x8 v;
            #pragma unroll
            for (int j = 0; j < 8; ++j) {
                const int cin = q * 8 + j;
                v[j] = (short)f2bf_rne(wk[(k * CIN + cin) * COUT + col]);
            }
            *(bf16x8*)(wt2 + t * 8) = v;
        }
    }
}

// ---------------------------------------------------------------------------
// Main MFMA kernel, software-pipelined: midx prefetch +3, gather prefetch +2,
// B-frag prefetch +1. Barrier-free, no LDS. Wave = 32 rows x 64 couts.
// ---------------------------------------------------------------------------
template<bool USE_MIDX>
__global__ __launch_bounds__(256) void conv_mfma2(
    const unsigned short* __restrict__ featb,   // [N][CIN] bf16
    const int*            __restrict__ midx,    // [K][N] (USE_MIDX)
    const int*            __restrict__ nmap,    // [K][N] (!USE_MIDX)
    const unsigned char*  __restrict__ mask8,
    const int*            __restrict__ mask32,
    const unsigned short* __restrict__ wt2,     // fragment-order weights
    float* __restrict__ out, int n, const int* __restrict__ flag)
{
    const int tid  = threadIdx.x;
    const int wave = tid >> 6;
    const int lane = tid & 63;
    const int lrow = lane & 15;
    const int q    = lane >> 4;
    const int n0   = blockIdx.x * 128 + wave * 32;
    int is_b8 = 0;
    if (!USE_MIDX) is_b8 = *flag;

    const int row0 = n0 + lrow, row1 = n0 + 16 + lrow;
    const bool vr0 = row0 < n, vr1 = row1 < n;

    auto load_mi = [&](int k, int rt) -> int {
        const int  r = rt ? row1 : row0;
        const bool v = rt ? vr1 : vr0;
        if (!v) return -1;
        const int idx = k * n + r;
        if (USE_MIDX) return midx[idx];
        const int m = is_b8 ? (int)mask8[idx] : mask32[idx];
        return m ? nmap[idx] : -1;
    };
    auto gather = [&](int mi) -> bf16x8 {
        bf16x8 z = {0, 0, 0, 0, 0, 0, 0, 0};
        if (mi >= 0) z = *(const bf16x8*)(featb + (size_t)mi * CIN + q * 8);
        return z;
    };

    bf16x8 B_buf[2][4];
    auto loadB = [&](int k, bf16x8* dst) {
        const unsigned short* p = wt2 + (k << 11) + lane * 8;  // (k*4+ct)*512
        #pragma unroll
        for (int ct = 0; ct < 4; ++ct) dst[ct] = *(const bf16x8*)(p + (ct << 9));
    };

    int    mi_buf[2][2];
    bf16x8 a_buf[3][2];
    f32x4  acc[2][4] = {};

    // prologue: a[0], a[1] gathered; mi[2] in slot 0; B[0] loaded
    {
        int t0 = load_mi(0, 0), t1 = load_mi(0, 1);
        int u0 = load_mi(1, 0), u1 = load_mi(1, 1);
        mi_buf[0][0] = load_mi(2, 0);
        mi_buf[0][1] = load_mi(2, 1);
        a_buf[0][0] = gather(t0); a_buf[0][1] = gather(t1);
        a_buf[1][0] = gather(u0); a_buf[1][1] = gather(u1);
        loadB(0, B_buf[0]);
    }

    #pragma unroll
    for (int k = 0; k < K_OFF; ++k) {
        if (k + 3 < K_OFF) {                         // midx[k+3] -> slot (k+1)&1
            mi_buf[(k + 1) & 1][0] = load_mi(k + 3, 0);
            mi_buf[(k + 1) & 1][1] = load_mi(k + 3, 1);
        }
        if (k + 2 < K_OFF) {                         // a[k+2] from midx[k+2] (slot k&1)
            a_buf[(k + 2) % 3][0] = gather(mi_buf[k & 1][0]);
            a_buf[(k + 2) % 3][1] = gather(mi_buf[k & 1][1]);
        }
        if (k + 1 < K_OFF) loadB(k + 1, B_buf[(k + 1) & 1]);

        const int s = k % 3, bs = k & 1;
        #pragma unroll
        for (int ct = 0; ct < 4; ++ct) {
            acc[0][ct] = __builtin_amdgcn_mfma_f32_16x16x32_bf16(
                a_buf[s][0], B_buf[bs][ct], acc[0][ct], 0, 0, 0);
            acc[1][ct] = __builtin_amdgcn_mfma_f32_16x16x32_bf16(
                a_buf[s][1], B_buf[bs][ct], acc[1][ct], 0, 0, 0);
        }
    }

    // epilogue: C/D layout col=lane&15, row=q*4+reg
    #pragma unroll
    for (int rt = 0; rt < 2; ++rt)
        #pragma unroll
        for (int ct = 0; ct < 4; ++ct)
            #pragma unroll
            for (int r = 0; r < 4; ++r) {
                const int row = n0 + rt * 16 + q * 4 + r;
                if (row < n) out[(size_t)row * COUT + ct * 16 + lrow] = acc[rt][ct][r];
            }
}

// ---------------------------------------------------------------------------
// fp32 fallback (round-1 kernel) if ws is too small for bf16 staging.
// ---------------------------------------------------------------------------
#define BN 64
__global__ __launch_bounds__(256) void sparse_conv_fp32(
    const float* __restrict__ feat, const int* __restrict__ nmap,
    const unsigned char* __restrict__ mask8, const int* __restrict__ mask32,
    const float* __restrict__ wk, float* __restrict__ out,
    int n, const int* __restrict__ flag)
{
    __shared__ float A[CIN][BN];
    __shared__ float W[CIN][COUT];
    const int tid = threadIdx.x;
    const int n0 = blockIdx.x * BN;
    const int is_b8 = *flag;
    const int r0 = (tid >> 4) * 4, c0 = (tid & 15) * 4;
    const int grow = tid >> 2, gpart = tid & 3;
    float acc[4][4] = {};
    for (int k = 0; k < K_OFF; ++k) {
        {
            const int base = tid * 8;
            const float* wsrc = wk + (size_t)k * (CIN * COUT) + base;
            float4 w0 = ((const float4*)wsrc)[0];
            float4 w1 = ((const float4*)wsrc)[1];
            *(float4*)&W[base >> 6][base & 63] = w0;
            *(float4*)&W[base >> 6][(base & 63) + 4] = w1;
        }
        {
            const int gn = n0 + grow;
            float4 f0 = make_float4(0.f, 0.f, 0.f, 0.f), f1 = f0;
            if (gn < n) {
                const int idx = k * n + gn;
                const int m = is_b8 ? (int)mask8[idx] : mask32[idx];
                if (m) {
                    const float* fsrc = feat + (size_t)nmap[idx] * CIN + gpart * 8;
                    f0 = ((const float4*)fsrc)[0];
                    f1 = ((const float4*)fsrc)[1];
                }
            }
            const int cb = gpart * 8;
            A[cb+0][grow]=f0.x; A[cb+1][grow]=f0.y; A[cb+2][grow]=f0.z; A[cb+3][grow]=f0.w;
            A[cb+4][grow]=f1.x; A[cb+5][grow]=f1.y; A[cb+6][grow]=f1.z; A[cb+7][grow]=f1.w;
        }
        __syncthreads();
        #pragma unroll
        for (int c = 0; c < CIN; ++c) {
            const float4 a = *(const float4*)&A[c][r0];
            const float4 w = *(const float4*)&W[c][c0];
            acc[0][0]+=a.x*w.x; acc[0][1]+=a.x*w.y; acc[0][2]+=a.x*w.z; acc[0][3]+=a.x*w.w;
            acc[1][0]+=a.y*w.x; acc[1][1]+=a.y*w.y; acc[1][2]+=a.y*w.z; acc[1][3]+=a.y*w.w;
            acc[2][0]+=a.z*w.x; acc[2][1]+=a.z*w.y; acc[2][2]+=a.z*w.z; acc[2][3]+=a.z*w.w;
            acc[3][0]+=a.w*w.x; acc[3][1]+=a.w*w.y; acc[3][2]+=a.w*w.z; acc[3][3]+=a.w*w.w;
        }
        __syncthreads();
    }
    #pragma unroll
    for (int i = 0; i < 4; ++i) {
        const int orow = n0 + r0 + i;
        if (orow < n)
            *(float4*)&out[(size_t)orow * COUT + c0] =
                make_float4(acc[i][0], acc[i][1], acc[i][2], acc[i][3]);
    }
}

static inline size_t align16(size_t x) { return (x + 15) & ~(size_t)15; }

extern "C" void kernel_launch(void* const* d_in, const int* in_sizes, int n_in,
                              void* d_out, int out_size, void* d_ws, size_t ws_size,
                              hipStream_t stream) {
    const float*         feat = (const float*)d_in[0];
    const int*           nmap = (const int*)d_in[1];
    const unsigned char* m8   = (const unsigned char*)d_in[2];
    const int*           m32  = (const int*)d_in[2];
    const float*         wk   = (const float*)d_in[3];
    float*               out  = (float*)d_out;

    const int n = in_sizes[0] / CIN;
    int* flag = (int*)d_ws;

    const size_t feat_off   = 128;
    const size_t feat_bytes = (size_t)n * CIN * 2;
    const size_t midx_off   = align16(feat_off + feat_bytes);
    const size_t midx_bytes = (size_t)K_OFF * n * 4;
    const size_t wt2_bytes  = (size_t)K_OFF * 4 * 64 * 8 * 2;

    const size_t need_full   = align16(midx_off + midx_bytes) + wt2_bytes;
    const size_t need_nomidx = midx_off + wt2_bytes;

    const int mask_elems = K_OFF * n;
    const int det_bytes  = mask_elems < 65536 ? mask_elems : 65536;
    detect_mask<<<1, 1024, 0, stream>>>(m8, det_bytes, flag);

    const int Bf = (n * CIN / 8 + 255) / 256;
    const int Bw = (K_OFF * 4 * 64 + 255) / 256;
    const int nblocks = (n + 127) / 128;

    if (ws_size >= need_full) {
        unsigned short* featb = (unsigned short*)((char*)d_ws + feat_off);
        int*            midx  = (int*)((char*)d_ws + midx_off);
        unsigned short* wt2   = (unsigned short*)((char*)d_ws + align16(midx_off + midx_bytes));
        const int Bm = ((K_OFF * n + 3) / 4 + 255) / 256;
        prep_kernel<<<Bf + Bm + Bw, 256, 0, stream>>>(
            feat, nmap, m8, m32, wk, featb, midx, wt2, n, Bf, Bm, flag);
        conv_mfma2<true><<<nblocks, 256, 0, stream>>>(
            featb, midx, nmap, m8, m32, wt2, out, n, flag);
    } else if (ws_size >= need_nomidx) {
        unsigned short* featb = (unsigned short*)((char*)d_ws + feat_off);
        unsigned short* wt2   = (unsigned short*)((char*)d_ws + midx_off);
        prep_kernel<<<Bf + Bw, 256, 0, stream>>>(
            feat, nmap, m8, m32, wk, featb, (int*)nullptr, wt2, n, Bf, 0, flag);
        conv_mfma2<false><<<nblocks, 256, 0, stream>>>(
            featb, (const int*)nullptr, nmap, m8, m32, wt2, out, n, flag);
    } else {
        const int nb = (n + BN - 1) / BN;
        sparse_conv_fp32<<<nb, 256, 0, stream>>>(feat, nmap, m8, m32, wk, out, n, flag);
    }
}

// Round 4
// 183.002 us; speedup vs baseline: 2.5807x; 1.0243x over previous
//
#include <hip/hip_runtime.h>

#define CIN   32
#define COUT  64
#define K_OFF 27

typedef __attribute__((ext_vector_type(8))) short bf16x8;
typedef __attribute__((ext_vector_type(4))) float f32x4;

__device__ inline unsigned short f2bf_rne(float f) {
    union { float f; unsigned int u; } v; v.f = f;
    unsigned int u = v.u;
    u = (u + 0x7fffu + ((u >> 16) & 1u)) >> 16;
    return (unsigned short)u;
}

// ---------------------------------------------------------------------------
// Mask-dtype detect on first 4KB only (mask ~50% ones => decisive): any
// nonzero byte at offset %4 != 0  =>  1-byte bool (flag=1), else int32 (0).
// ---------------------------------------------------------------------------
__global__ __launch_bounds__(256) void detect_mask(
    const unsigned char* __restrict__ mask, int nbytes, int* __restrict__ flag) {
    __shared__ int wany[4];
    int found = 0;
    for (int i = threadIdx.x; i < nbytes; i += 256)
        if ((i & 3) && mask[i]) found = 1;
    unsigned long long b = __ballot(found);
    if ((threadIdx.x & 63) == 0) wany[threadIdx.x >> 6] = b ? 1 : 0;
    __syncthreads();
    if (threadIdx.x == 0) *flag = wany[0] | wany[1] | wany[2] | wany[3];
}

// ---------------------------------------------------------------------------
// Prep: [0,Bf) feat fp32->bf16 | [Bf,..) weights -> fragment-order bf16
// wt2[k][ct][lane][8] so a wave's B-frag load is lane-contiguous 1KB.
// ---------------------------------------------------------------------------
__global__ __launch_bounds__(256) void prep_kernel(
    const float* __restrict__ feat, const float* __restrict__ wk,
    unsigned short* __restrict__ featb, unsigned short* __restrict__ wt2,
    int n, int Bf)
{
    const int gid = blockIdx.x;
    if (gid < Bf) {
        const int base = (gid * 256 + threadIdx.x) * 8;
        if (base < n * CIN) {
            float4 a = *(const float4*)(feat + base);
            float4 b = *(const float4*)(feat + base + 4);
            bf16x8 v;
            v[0] = (short)f2bf_rne(a.x); v[1] = (short)f2bf_rne(a.y);
            v[2] = (short)f2bf_rne(a.z); v[3] = (short)f2bf_rne(a.w);
            v[4] = (short)f2bf_rne(b.x); v[5] = (short)f2bf_rne(b.y);
            v[6] = (short)f2bf_rne(b.z); v[7] = (short)f2bf_rne(b.w);
            *(bf16x8*)(featb + base) = v;
        }
    } else {
        const int t = (gid - Bf) * 256 + threadIdx.x;   // fragment slot id
        if (t < K_OFF * 4 * 64) {
            const int lane = t & 63, ct = (t >> 6) & 3, k = t >> 8;
            const int lrow = lane & 15, q = lane >> 4;
            const int col = ct * 16 + lrow;
            bf16x8 v;
            #pragma unroll
            for (int j = 0; j < 8; ++j)
                v[j] = (short)f2bf_rne(wk[(k * CIN + q * 8 + j) * COUT + col]);
            *(bf16x8*)(wt2 + t * 8) = v;
        }
    }
}

// ---------------------------------------------------------------------------
// Main MFMA kernel. Barrier-free, no LDS staging. Block = 4 waves; wave owns
// 64 rows x 64 couts (4 row-frags, 16 MFMA/iter, B reused 4x). Per iter:
//   1 nmap + 1 mask load (rows n0w+lane, contiguous), 4 __shfl to distribute,
//   4 masked gathers (16B/lane), 4 B-frag loads (lane-contiguous 1KB).
// Pipeline: midx +3, gathers +2 (3 slots), B +1 (2 slots). Issue order keeps
// B older than the younger prefetches so MFMA's vmcnt wait never drains them.
// ---------------------------------------------------------------------------
__global__ __launch_bounds__(256) void conv_mfma3(
    const unsigned short* __restrict__ featb,   // [N][CIN] bf16
    const int*            __restrict__ nmap,    // [K][N]
    const unsigned char*  __restrict__ maskb,   // byte view of mask
    const unsigned short* __restrict__ wt2,     // fragment-order weights
    float* __restrict__ out, int n, const int* __restrict__ flag)
{
    const int tid  = threadIdx.x;
    const int wave = tid >> 6;
    const int lane = tid & 63;
    const int lrow = lane & 15;
    const int q    = lane >> 4;
    const int n0w  = blockIdx.x * 256 + wave * 64;
    const int mshift = (*flag) ? 0 : 2;   // bool: stride 1; int32: low byte

    const int  myrow  = n0w + lane;
    const bool rvalid = myrow < n;

    auto load_mi = [&](int k) -> int {
        if (!rvalid) return -1;
        const int idx = k * n + myrow;
        const unsigned char mv = maskb[(size_t)idx << mshift];
        const int nm = nmap[idx];
        return mv ? nm : -1;
    };
    auto do_gathers = [&](int mi_raw, bf16x8* dst) {
        #pragma unroll
        for (int rt = 0; rt < 4; ++rt) {
            const int mi = __shfl(mi_raw, rt * 16 + lrow);
            bf16x8 v = {0, 0, 0, 0, 0, 0, 0, 0};
            if (mi >= 0) v = *(const bf16x8*)(featb + (size_t)mi * CIN + q * 8);
            dst[rt] = v;
        }
    };
    auto loadB = [&](int k, bf16x8* dst) {
        const unsigned short* p = wt2 + ((k * 4) << 9) + lane * 8;
        #pragma unroll
        for (int ct = 0; ct < 4; ++ct) dst[ct] = *(const bf16x8*)(p + (ct << 9));
    };

    int    mi_buf[2];
    bf16x8 a_buf[3][4];
    bf16x8 B_buf[2][4];
    f32x4  acc[4][4] = {};

    // prologue
    {
        const int m0 = load_mi(0);
        const int m1 = load_mi(1);
        mi_buf[0] = load_mi(2);
        loadB(0, B_buf[0]);
        do_gathers(m0, a_buf[0]);
        do_gathers(m1, a_buf[1]);
    }

    #pragma unroll
    for (int k = 0; k < K_OFF; ++k) {
        if (k + 3 < K_OFF) mi_buf[(k + 1) & 1] = load_mi(k + 3);
        if (k + 2 < K_OFF) do_gathers(mi_buf[k & 1], a_buf[(k + 2) % 3]);
        if (k + 1 < K_OFF) loadB(k + 1, B_buf[(k + 1) & 1]);

        const int s = k % 3, bs = k & 1;
        #pragma unroll
        for (int rt = 0; rt < 4; ++rt)
            #pragma unroll
            for (int ct = 0; ct < 4; ++ct)
                acc[rt][ct] = __builtin_amdgcn_mfma_f32_16x16x32_bf16(
                    a_buf[s][rt], B_buf[bs][ct], acc[rt][ct], 0, 0, 0);
    }

    // epilogue: C/D layout col=lane&15, row=q*4+reg
    #pragma unroll
    for (int rt = 0; rt < 4; ++rt)
        #pragma unroll
        for (int ct = 0; ct < 4; ++ct)
            #pragma unroll
            for (int r = 0; r < 4; ++r) {
                const int row = n0w + rt * 16 + q * 4 + r;
                if (row < n) out[(size_t)row * COUT + ct * 16 + lrow] = acc[rt][ct][r];
            }
}

// ---------------------------------------------------------------------------
// fp32 fallback (round-1 kernel) if ws is too small for bf16 staging.
// ---------------------------------------------------------------------------
#define BN 64
__global__ __launch_bounds__(256) void sparse_conv_fp32(
    const float* __restrict__ feat, const int* __restrict__ nmap,
    const unsigned char* __restrict__ mask8, const int* __restrict__ mask32,
    const float* __restrict__ wk, float* __restrict__ out,
    int n, const int* __restrict__ flag)
{
    __shared__ float A[CIN][BN];
    __shared__ float W[CIN][COUT];
    const int tid = threadIdx.x;
    const int n0 = blockIdx.x * BN;
    const int is_b8 = *flag;
    const int r0 = (tid >> 4) * 4, c0 = (tid & 15) * 4;
    const int grow = tid >> 2, gpart = tid & 3;
    float acc[4][4] = {};
    for (int k = 0; k < K_OFF; ++k) {
        {
            const int base = tid * 8;
            const float* wsrc = wk + (size_t)k * (CIN * COUT) + base;
            float4 w0 = ((const float4*)wsrc)[0];
            float4 w1 = ((const float4*)wsrc)[1];
            *(float4*)&W[base >> 6][base & 63] = w0;
            *(float4*)&W[base >> 6][(base & 63) + 4] = w1;
        }
        {
            const int gn = n0 + grow;
            float4 f0 = make_float4(0.f, 0.f, 0.f, 0.f), f1 = f0;
            if (gn < n) {
                const int idx = k * n + gn;
                const int m = is_b8 ? (int)mask8[idx] : mask32[idx];
                if (m) {
                    const float* fsrc = feat + (size_t)nmap[idx] * CIN + gpart * 8;
                    f0 = ((const float4*)fsrc)[0];
                    f1 = ((const float4*)fsrc)[1];
                }
            }
            const int cb = gpart * 8;
            A[cb+0][grow]=f0.x; A[cb+1][grow]=f0.y; A[cb+2][grow]=f0.z; A[cb+3][grow]=f0.w;
            A[cb+4][grow]=f1.x; A[cb+5][grow]=f1.y; A[cb+6][grow]=f1.z; A[cb+7][grow]=f1.w;
        }
        __syncthreads();
        #pragma unroll
        for (int c = 0; c < CIN; ++c) {
            const float4 a = *(const float4*)&A[c][r0];
            const float4 w = *(const float4*)&W[c][c0];
            acc[0][0]+=a.x*w.x; acc[0][1]+=a.x*w.y; acc[0][2]+=a.x*w.z; acc[0][3]+=a.x*w.w;
            acc[1][0]+=a.y*w.x; acc[1][1]+=a.y*w.y; acc[1][2]+=a.y*w.z; acc[1][3]+=a.y*w.w;
            acc[2][0]+=a.z*w.x; acc[2][1]+=a.z*w.y; acc[2][2]+=a.z*w.z; acc[2][3]+=a.z*w.w;
            acc[3][0]+=a.w*w.x; acc[3][1]+=a.w*w.y; acc[3][2]+=a.w*w.z; acc[3][3]+=a.w*w.w;
        }
        __syncthreads();
    }
    #pragma unroll
    for (int i = 0; i < 4; ++i) {
        const int orow = n0 + r0 + i;
        if (orow < n)
            *(float4*)&out[(size_t)orow * COUT + c0] =
                make_float4(acc[i][0], acc[i][1], acc[i][2], acc[i][3]);
    }
}

static inline size_t align16(size_t x) { return (x + 15) & ~(size_t)15; }

extern "C" void kernel_launch(void* const* d_in, const int* in_sizes, int n_in,
                              void* d_out, int out_size, void* d_ws, size_t ws_size,
                              hipStream_t stream) {
    const float*         feat = (const float*)d_in[0];
    const int*           nmap = (const int*)d_in[1];
    const unsigned char* m8   = (const unsigned char*)d_in[2];
    const int*           m32  = (const int*)d_in[2];
    const float*         wk   = (const float*)d_in[3];
    float*               out  = (float*)d_out;

    const int n = in_sizes[0] / CIN;
    int* flag = (int*)d_ws;

    const size_t feat_off   = 128;
    const size_t feat_bytes = (size_t)n * CIN * 2;
    const size_t wt2_off    = align16(feat_off + feat_bytes);
    const size_t wt2_bytes  = (size_t)K_OFF * 4 * 64 * 8 * 2;
    const size_t needed     = wt2_off + wt2_bytes;

    const int mask_elems = K_OFF * n;
    const int det_bytes  = mask_elems < 4096 ? mask_elems : 4096;
    detect_mask<<<1, 256, 0, stream>>>(m8, det_bytes, flag);

    if (ws_size >= needed) {
        unsigned short* featb = (unsigned short*)((char*)d_ws + feat_off);
        unsigned short* wt2   = (unsigned short*)((char*)d_ws + wt2_off);
        const int Bf = (n * CIN / 8 + 255) / 256;
        const int Bw = (K_OFF * 4 * 64 + 255) / 256;
        prep_kernel<<<Bf + Bw, 256, 0, stream>>>(feat, wk, featb, wt2, n, Bf);
        const int nblocks = (n + 255) / 256;
        conv_mfma3<<<nblocks, 256, 0, stream>>>(featb, nmap, m8, wt2, out, n, flag);
    } else {
        const int nb = (n + BN - 1) / BN;
        sparse_conv_fp32<<<nb, 256, 0, stream>>>(feat, nmap, m8, m32, wk, out, n, flag);
    }
}